// Round 1
// baseline (844.324 us; speedup 1.0000x reference)
//
#include <hip/hip_runtime.h>

// ScaledAttention: B=8, T=2048, D=1024, single "head" over full D, SCALE=1/8.
// Pipeline: cvt f32->f16 -> 3x proj GEMM (V transposed) -> softmax/P -> PV GEMM.

typedef float f32x4 __attribute__((ext_vector_type(4)));
typedef _Float16 half8 __attribute__((ext_vector_type(8)));
typedef _Float16 half4 __attribute__((ext_vector_type(4)));

#define DEVINL __device__ __forceinline__

static constexpr float ATT_SCALE = 0.125f;  // 1/sqrt(1024/16)

DEVINL void gload_lds16(const _Float16* g, _Float16* l) {
  __builtin_amdgcn_global_load_lds((const __attribute__((address_space(1))) void*)g,
                                   (__attribute__((address_space(3))) void*)l, 16, 0, 0);
}

// Stage a (NCH*8/64)-row x 64-col fp16 tile (row-major, leading dim ld) into LDS.
// NCH = number of 16B chunks; NTHR = blockDim.x. LDS layout is linear [row][64].
template<int NCH, int NTHR>
DEVINL void stage_tile(const _Float16* __restrict__ g0, int ld, _Float16* lds, int tid) {
  const int w = tid >> 6;
#pragma unroll
  for (int i = 0; i < NCH / NTHR; ++i) {
    const int c = i * NTHR + tid;
    gload_lds16(g0 + (size_t)(c >> 3) * ld + (c & 7) * 8,
                lds + (size_t)(i * NTHR + w * 64) * 8);
  }
}

__global__ __launch_bounds__(256) void cvt_f32_f16(const float* __restrict__ in,
                                                   _Float16* __restrict__ out, int n8) {
  int i = blockIdx.x * 256 + threadIdx.x;
  if (i >= n8) return;
  const float4* p = (const float4*)in + (size_t)i * 2;
  float4 v0 = p[0], v1 = p[1];
  half8 h;
  h[0] = (_Float16)v0.x; h[1] = (_Float16)v0.y; h[2] = (_Float16)v0.z; h[3] = (_Float16)v0.w;
  h[4] = (_Float16)v1.x; h[5] = (_Float16)v1.y; h[6] = (_Float16)v1.z; h[7] = (_Float16)v1.w;
  *((half8*)out + i) = h;
}

// C[m,n] = sum_k A[m,k]*Bw[n,k] + bias[n].  M=16384, N=1024, K=1024.
// MODE 0: Out row-major [16384][1024].  MODE 1: Out = V^T per batch [8][1024][2048].
template<int MODE>
__global__ __launch_bounds__(256) void gemm_proj(const _Float16* __restrict__ A,
                                                 const _Float16* __restrict__ Bw,
                                                 const float* __restrict__ bias,
                                                 _Float16* __restrict__ Out) {
  __shared__ _Float16 sA[128 * 64];
  __shared__ _Float16 sB[128 * 64];
  const int tid = threadIdx.x, l = tid & 63, w = tid >> 6;
  const int nt = blockIdx.x, mt = blockIdx.y;
  const int wr = (w >> 1) * 64, wc = (w & 1) * 64;
  const int lr = l & 15, lk = l >> 4;
  f32x4 acc[4][4] = {};
  const _Float16* Ab = A + (size_t)mt * 128 * 1024;
  const _Float16* Bb = Bw + (size_t)nt * 128 * 1024;
  for (int kt = 0; kt < 16; ++kt) {
    stage_tile<1024, 256>(Ab + kt * 64, 1024, sA, tid);
    stage_tile<1024, 256>(Bb + kt * 64, 1024, sB, tid);
    __syncthreads();
#pragma unroll
    for (int kk = 0; kk < 2; ++kk) {
      half8 a[4];
#pragma unroll
      for (int i = 0; i < 4; ++i)
        a[i] = *(const half8*)&sA[(wr + i * 16 + lr) * 64 + kk * 32 + lk * 8];
#pragma unroll
      for (int j = 0; j < 4; ++j) {
        half8 bf = *(const half8*)&sB[(wc + j * 16 + lr) * 64 + kk * 32 + lk * 8];
#pragma unroll
        for (int i = 0; i < 4; ++i)
          acc[i][j] = __builtin_amdgcn_mfma_f32_16x16x32_f16(a[i], bf, acc[i][j], 0, 0, 0);
      }
    }
    __syncthreads();
  }
  const int r0 = lk * 4;
#pragma unroll
  for (int j = 0; j < 4; ++j) {
    const int cg = nt * 128 + wc + j * 16 + lr;
    const float bv = bias[cg];
#pragma unroll
    for (int i = 0; i < 4; ++i) {
      const int rg = mt * 128 + wr + i * 16 + r0;
      if (MODE == 0) {
#pragma unroll
        for (int r = 0; r < 4; ++r)
          Out[(size_t)(rg + r) * 1024 + cg] = (_Float16)(acc[i][j][r] + bv);
      } else {
        const int bb = rg >> 11, t0 = rg & 2047;
        half4 v;
#pragma unroll
        for (int r = 0; r < 4; ++r) v[r] = (_Float16)(acc[i][j][r] + bv);
        *(half4*)&Out[((size_t)bb * 1024 + cg) * 2048 + t0] = v;
      }
    }
  }
}

// Per (batch, 32 q-rows): two-pass online softmax over causal k range; writes
// normalized P (fp16) including zeros above the diagonal within diagonal tiles.
__global__ __launch_bounds__(128) void attn_p(const _Float16* __restrict__ Qh,
                                              const _Float16* __restrict__ Kh,
                                              _Float16* __restrict__ P) {
  __shared__ _Float16 sQ[32 * 64];
  __shared__ _Float16 sK[128 * 64];
  const int tid = threadIdx.x, l = tid & 63, w = tid >> 6;  // 2 waves
  const int qt = 63 - blockIdx.x;  // heavy tiles first
  const int b = blockIdx.y;
  const int lr = l & 15, lk = l >> 4;
  const int jmax = (qt * 32 + 31) >> 7;
  const _Float16* Qb = Qh + ((size_t)b * 2048 + qt * 32) * 1024;
  const _Float16* Kb = Kh + (size_t)b * 2048 * 1024;
  float rmax[4], rsum[4];
#pragma unroll
  for (int r = 0; r < 4; ++r) { rmax[r] = -__builtin_inff(); rsum[r] = 0.f; }
  const int rowl = w * 16 + lk * 4;   // local row for reg r (+r)
  const int qrow = qt * 32 + rowl;    // row within batch
  for (int phase = 0; phase < 2; ++phase) {
    float rinv[4];
    if (phase == 1) {
#pragma unroll
      for (int r = 0; r < 4; ++r) rinv[r] = 1.f / rsum[r];
    }
    for (int j = 0; j <= jmax; ++j) {
      f32x4 acc[8] = {};
      for (int dt = 0; dt < 16; ++dt) {
        stage_tile<256, 128>(Qb + dt * 64, 1024, sQ, tid);
        stage_tile<1024, 128>(Kb + (size_t)j * 128 * 1024 + dt * 64, 1024, sK, tid);
        __syncthreads();
#pragma unroll
        for (int kk = 0; kk < 2; ++kk) {
          half8 a = *(const half8*)&sQ[(w * 16 + lr) * 64 + kk * 32 + lk * 8];
#pragma unroll
          for (int jf = 0; jf < 8; ++jf) {
            half8 bf = *(const half8*)&sK[(jf * 16 + lr) * 64 + kk * 32 + lk * 8];
            acc[jf] = __builtin_amdgcn_mfma_f32_16x16x32_f16(a, bf, acc[jf], 0, 0, 0);
          }
        }
        __syncthreads();
      }
      if (phase == 0) {
#pragma unroll
        for (int r = 0; r < 4; ++r) {
          const int q = qrow + r;
          float tmax = -__builtin_inff();
#pragma unroll
          for (int jf = 0; jf < 8; ++jf) {
            const int k = j * 128 + jf * 16 + lr;
            float s = (k <= q) ? acc[jf][r] * ATT_SCALE : -__builtin_inff();
            tmax = fmaxf(tmax, s);
          }
          for (int m = 1; m < 16; m <<= 1) tmax = fmaxf(tmax, __shfl_xor(tmax, m, 64));
          const float nm = fmaxf(rmax[r], tmax);
          float ps = 0.f;
#pragma unroll
          for (int jf = 0; jf < 8; ++jf) {
            const int k = j * 128 + jf * 16 + lr;
            float s = (k <= q) ? acc[jf][r] * ATT_SCALE : -__builtin_inff();
            ps += __expf(s - nm);
          }
          for (int m = 1; m < 16; m <<= 1) ps += __shfl_xor(ps, m, 64);
          rsum[r] = rsum[r] * __expf(rmax[r] - nm) + ps;
          rmax[r] = nm;
        }
      } else {
        _Float16* Pr = P + ((size_t)b * 2048 + qt * 32) * 2048;
#pragma unroll
        for (int r = 0; r < 4; ++r) {
          const int q = qrow + r;
#pragma unroll
          for (int jf = 0; jf < 8; ++jf) {
            const int k = j * 128 + jf * 16 + lr;
            const float p = (k <= q) ? __expf(acc[jf][r] * ATT_SCALE - rmax[r]) * rinv[r] : 0.f;
            Pr[(size_t)(rowl + r) * 2048 + k] = (_Float16)p;
          }
        }
      }
    }
  }
}

// O[b,q,d] = sum_k P[b,q,k] * VT[b,d,k], causal k range per q-tile.
__global__ __launch_bounds__(256) void gemm_pv(const _Float16* __restrict__ P,
                                               const _Float16* __restrict__ VT,
                                               float* __restrict__ O) {
  __shared__ _Float16 sA[128 * 64];
  __shared__ _Float16 sB[128 * 64];
  const int tid = threadIdx.x, l = tid & 63, w = tid >> 6;
  const int dt = blockIdx.x;       // 0..7
  const int qt = 15 - blockIdx.y;  // heavy first
  const int b = blockIdx.z;
  const int wr = (w >> 1) * 64, wc = (w & 1) * 64;
  const int lr = l & 15, lk = l >> 4;
  f32x4 acc[4][4] = {};
  const _Float16* Ab = P + ((size_t)b * 2048 + qt * 128) * 2048;
  const _Float16* Bb = VT + ((size_t)b * 1024 + dt * 128) * 2048;
  const int nk = (qt + 1) * 2;
  for (int kt = 0; kt < nk; ++kt) {
    stage_tile<1024, 256>(Ab + kt * 64, 2048, sA, tid);
    stage_tile<1024, 256>(Bb + kt * 64, 2048, sB, tid);
    __syncthreads();
#pragma unroll
    for (int kk = 0; kk < 2; ++kk) {
      half8 a[4];
#pragma unroll
      for (int i = 0; i < 4; ++i)
        a[i] = *(const half8*)&sA[(wr + i * 16 + lr) * 64 + kk * 32 + lk * 8];
#pragma unroll
      for (int j = 0; j < 4; ++j) {
        half8 bf = *(const half8*)&sB[(wc + j * 16 + lr) * 64 + kk * 32 + lk * 8];
#pragma unroll
        for (int i = 0; i < 4; ++i)
          acc[i][j] = __builtin_amdgcn_mfma_f32_16x16x32_f16(a[i], bf, acc[i][j], 0, 0, 0);
      }
    }
    __syncthreads();
  }
  const int r0 = lk * 4;
#pragma unroll
  for (int j = 0; j < 4; ++j) {
    const int cg = dt * 128 + wc + j * 16 + lr;
#pragma unroll
    for (int i = 0; i < 4; ++i) {
      const int rg = qt * 128 + wr + i * 16 + r0;
#pragma unroll
      for (int r = 0; r < 4; ++r)
        O[((size_t)b * 2048 + rg + r) * 1024 + cg] = acc[i][j][r];
    }
  }
}

extern "C" void kernel_launch(void* const* d_in, const int* in_sizes, int n_in,
                              void* d_out, int out_size, void* d_ws, size_t ws_size,
                              hipStream_t stream) {
  const float* x    = (const float*)d_in[0];
  const float* Wq_w = (const float*)d_in[1];
  const float* Wq_b = (const float*)d_in[2];
  const float* Wk_w = (const float*)d_in[3];
  const float* Wk_b = (const float*)d_in[4];
  const float* Wv_w = (const float*)d_in[5];
  const float* Wv_b = (const float*)d_in[6];
  float* out = (float*)d_out;
  char* ws = (char*)d_ws;
  // workspace layout (bytes)
  _Float16* Qh  = (_Float16*)(ws);              // 16384x1024 f16 = 32 MiB
  _Float16* Kh  = (_Float16*)(ws + 33554432);   // 32 MiB
  _Float16* VT  = (_Float16*)(ws + 67108864);   // [8][1024][2048] f16 = 32 MiB
  _Float16* Pp  = (_Float16*)(ws + 100663296);  // [8][2048][2048] f16 = 64 MiB
  _Float16* xh  = (_Float16*)(ws + 167772160);  // 32 MiB
  _Float16* Wqh = (_Float16*)(ws + 201326592);  // 2 MiB
  _Float16* Wkh = (_Float16*)(ws + 203423744);  // 2 MiB
  _Float16* Wvh = (_Float16*)(ws + 205520896);  // 2 MiB  (total ~198 MiB)

  cvt_f32_f16<<<8192, 256, 0, stream>>>(x, xh, 2097152);
  cvt_f32_f16<<<512, 256, 0, stream>>>(Wq_w, Wqh, 131072);
  cvt_f32_f16<<<512, 256, 0, stream>>>(Wk_w, Wkh, 131072);
  cvt_f32_f16<<<512, 256, 0, stream>>>(Wv_w, Wvh, 131072);
  gemm_proj<0><<<dim3(8, 128), 256, 0, stream>>>(xh, Wqh, Wq_b, Qh);
  gemm_proj<0><<<dim3(8, 128), 256, 0, stream>>>(xh, Wkh, Wk_b, Kh);
  gemm_proj<1><<<dim3(8, 128), 256, 0, stream>>>(xh, Wvh, Wv_b, VT);
  attn_p<<<dim3(64, 8), 128, 0, stream>>>(Qh, Kh, Pp);
  gemm_pv<<<dim3(8, 16, 8), 256, 0, stream>>>(Pp, VT, out);
}

// Round 2
// 383.988 us; speedup vs baseline: 2.1988x; 2.1988x over previous
//
#include <hip/hip_runtime.h>

// ScaledAttention: B=8, T=2048, D=1024, single "head" over full D, SCALE=1/8.
// Pipeline: cvt f32->f16 -> 3x proj GEMM (V transposed) -> causal QK^T GEMM
// (compact triangular f32 S) -> row softmax (in-register) -> PV GEMM.

typedef float f32x4 __attribute__((ext_vector_type(4)));
typedef _Float16 half8 __attribute__((ext_vector_type(8)));
typedef _Float16 half4 __attribute__((ext_vector_type(4)));
typedef _Float16 half2v __attribute__((ext_vector_type(2)));

#define DEVINL __device__ __forceinline__

static constexpr float ATT_SCALE = 0.125f;  // 1/sqrt(1024/16)

DEVINL void gload_lds16(const _Float16* g, _Float16* l) {
  __builtin_amdgcn_global_load_lds((const __attribute__((address_space(1))) void*)g,
                                   (__attribute__((address_space(3))) void*)l, 16, 0, 0);
}

// Stage a (NCH*8/64)-row x 64-col fp16 tile (row-major, leading dim ld) into LDS.
// NCH = number of 16B chunks; NTHR = blockDim.x. LDS layout is linear [row][64].
template<int NCH, int NTHR>
DEVINL void stage_tile(const _Float16* __restrict__ g0, int ld, _Float16* lds, int tid) {
  const int w = tid >> 6;
#pragma unroll
  for (int i = 0; i < NCH / NTHR; ++i) {
    const int c = i * NTHR + tid;
    gload_lds16(g0 + (size_t)(c >> 3) * ld + (c & 7) * 8,
                lds + (size_t)(i * NTHR + w * 64) * 8);
  }
}

__global__ __launch_bounds__(256) void cvt_f32_f16(const float* __restrict__ in,
                                                   _Float16* __restrict__ out, int n8) {
  int i = blockIdx.x * 256 + threadIdx.x;
  if (i >= n8) return;
  const float4* p = (const float4*)in + (size_t)i * 2;
  float4 v0 = p[0], v1 = p[1];
  half8 h;
  h[0] = (_Float16)v0.x; h[1] = (_Float16)v0.y; h[2] = (_Float16)v0.z; h[3] = (_Float16)v0.w;
  h[4] = (_Float16)v1.x; h[5] = (_Float16)v1.y; h[6] = (_Float16)v1.z; h[7] = (_Float16)v1.w;
  *((half8*)out + i) = h;
}

// C[m,n] = sum_k A[m,k]*Bw[n,k] + bias[n].  M=16384, N=1024, K=1024.
// MODE 0: Out row-major [16384][1024].  MODE 1: Out = V^T per batch [8][1024][2048].
template<int MODE>
__global__ __launch_bounds__(256) void gemm_proj(const _Float16* __restrict__ A,
                                                 const _Float16* __restrict__ Bw,
                                                 const float* __restrict__ bias,
                                                 _Float16* __restrict__ Out) {
  __shared__ _Float16 sA[128 * 64];
  __shared__ _Float16 sB[128 * 64];
  const int tid = threadIdx.x, l = tid & 63, w = tid >> 6;
  const int nt = blockIdx.x, mt = blockIdx.y;
  const int wr = (w >> 1) * 64, wc = (w & 1) * 64;
  const int lr = l & 15, lk = l >> 4;
  f32x4 acc[4][4] = {};
  const _Float16* Ab = A + (size_t)mt * 128 * 1024;
  const _Float16* Bb = Bw + (size_t)nt * 128 * 1024;
  for (int kt = 0; kt < 16; ++kt) {
    stage_tile<1024, 256>(Ab + kt * 64, 1024, sA, tid);
    stage_tile<1024, 256>(Bb + kt * 64, 1024, sB, tid);
    __syncthreads();
#pragma unroll
    for (int kk = 0; kk < 2; ++kk) {
      half8 a[4];
#pragma unroll
      for (int i = 0; i < 4; ++i)
        a[i] = *(const half8*)&sA[(wr + i * 16 + lr) * 64 + kk * 32 + lk * 8];
#pragma unroll
      for (int j = 0; j < 4; ++j) {
        half8 bf = *(const half8*)&sB[(wc + j * 16 + lr) * 64 + kk * 32 + lk * 8];
#pragma unroll
        for (int i = 0; i < 4; ++i)
          acc[i][j] = __builtin_amdgcn_mfma_f32_16x16x32_f16(a[i], bf, acc[i][j], 0, 0, 0);
      }
    }
    __syncthreads();
  }
  const int r0 = lk * 4;
#pragma unroll
  for (int j = 0; j < 4; ++j) {
    const int cg = nt * 128 + wc + j * 16 + lr;
    const float bv = bias[cg];
#pragma unroll
    for (int i = 0; i < 4; ++i) {
      const int rg = mt * 128 + wr + i * 16 + r0;
      if (MODE == 0) {
#pragma unroll
        for (int r = 0; r < 4; ++r)
          Out[(size_t)(rg + r) * 1024 + cg] = (_Float16)(acc[i][j][r] + bv);
      } else {
        const int bb = rg >> 11, t0 = rg & 2047;
        half4 v;
#pragma unroll
        for (int r = 0; r < 4; ++r) v[r] = (_Float16)(acc[i][j][r] + bv);
        *(half4*)&Out[((size_t)bb * 1024 + cg) * 2048 + t0] = v;
      }
    }
  }
}

// Causal QK^T: blockIdx.x = triangular tile index (qt,jt with jt<=qt),
// blockIdx.y = batch. Writes compact S tiles [b][tri][128][128] f32,
// scaled, -inf above the diagonal.
__global__ __launch_bounds__(256) void gemm_qk(const _Float16* __restrict__ Qh,
                                               const _Float16* __restrict__ Kh,
                                               float* __restrict__ Sc) {
  __shared__ _Float16 sA[128 * 64];
  __shared__ _Float16 sB[128 * 64];
  const int tid = threadIdx.x, l = tid & 63, w = tid >> 6;
  const int idx = blockIdx.x, b = blockIdx.y;
  int qt = (int)((sqrtf(8.f * idx + 1.f) - 1.f) * 0.5f);
  while ((qt + 1) * (qt + 2) / 2 <= idx) ++qt;
  while (qt * (qt + 1) / 2 > idx) --qt;
  const int jt = idx - qt * (qt + 1) / 2;
  const int wr = (w >> 1) * 64, wc = (w & 1) * 64;
  const int lr = l & 15, lk = l >> 4;
  f32x4 acc[4][4] = {};
  const _Float16* Ab = Qh + ((size_t)b * 2048 + qt * 128) * 1024;
  const _Float16* Bb = Kh + ((size_t)b * 2048 + jt * 128) * 1024;
  for (int kt = 0; kt < 16; ++kt) {
    stage_tile<1024, 256>(Ab + kt * 64, 1024, sA, tid);
    stage_tile<1024, 256>(Bb + kt * 64, 1024, sB, tid);
    __syncthreads();
#pragma unroll
    for (int kk = 0; kk < 2; ++kk) {
      half8 a[4];
#pragma unroll
      for (int i = 0; i < 4; ++i)
        a[i] = *(const half8*)&sA[(wr + i * 16 + lr) * 64 + kk * 32 + lk * 8];
#pragma unroll
      for (int j = 0; j < 4; ++j) {
        half8 bf = *(const half8*)&sB[(wc + j * 16 + lr) * 64 + kk * 32 + lk * 8];
#pragma unroll
        for (int i = 0; i < 4; ++i)
          acc[i][j] = __builtin_amdgcn_mfma_f32_16x16x32_f16(a[i], bf, acc[i][j], 0, 0, 0);
      }
    }
    __syncthreads();
  }
  float* St = Sc + ((size_t)b * 136 + idx) * 16384;
  const int r0 = lk * 4;
#pragma unroll
  for (int j = 0; j < 4; ++j) {
    const int ck = wc + j * 16 + lr;
    const int kg = jt * 128 + ck;
#pragma unroll
    for (int i = 0; i < 4; ++i) {
#pragma unroll
      for (int r = 0; r < 4; ++r) {
        const int rq = wr + i * 16 + r0 + r;
        const int qg = qt * 128 + rq;
        St[(size_t)rq * 128 + ck] =
            (kg <= qg) ? acc[i][j][r] * ATT_SCALE : -__builtin_inff();
      }
    }
  }
}

// One wave per row. Reads compact f32 S (row spread over qt+1 tiles), computes
// softmax fully in registers, writes compact f16 P (zeros above diagonal).
__global__ __launch_bounds__(256) void softmax_p(const float* __restrict__ Sc,
                                                 _Float16* __restrict__ Pc) {
  const int l = threadIdx.x & 63;
  const int gid = blockIdx.x * 4 + (threadIdx.x >> 6);
  const int b = gid >> 11, q = gid & 2047;
  const int qt = q >> 7, rq = q & 127;
  const int nt = qt + 1;
  const size_t rowoff = ((size_t)b * 136 + (size_t)(qt * (qt + 1) / 2)) * 16384 +
                        (size_t)rq * 128 + l * 2;
  float vx[32];
  float m = -__builtin_inff();
#pragma unroll
  for (int c = 0; c < 16; ++c) {
    float x0 = -__builtin_inff(), x1 = -__builtin_inff();
    if (c < nt) {
      float2 t = *(const float2*)&Sc[rowoff + (size_t)c * 16384];
      x0 = t.x; x1 = t.y;
    }
    vx[2 * c] = x0; vx[2 * c + 1] = x1;
    m = fmaxf(m, fmaxf(x0, x1));
  }
#pragma unroll
  for (int s = 1; s < 64; s <<= 1) m = fmaxf(m, __shfl_xor(m, s, 64));
  float sum = 0.f;
#pragma unroll
  for (int i = 0; i < 32; ++i) { vx[i] = __expf(vx[i] - m); sum += vx[i]; }
#pragma unroll
  for (int s = 1; s < 64; s <<= 1) sum += __shfl_xor(sum, s, 64);
  const float inv = 1.f / sum;
  _Float16* Pb = Pc + ((size_t)b * 136 + (size_t)(qt * (qt + 1) / 2)) * 16384 +
                 (size_t)rq * 128 + l * 2;
#pragma unroll
  for (int c = 0; c < 16; ++c) {
    if (c < nt) {
      half2v p;
      p[0] = (_Float16)(vx[2 * c] * inv);
      p[1] = (_Float16)(vx[2 * c + 1] * inv);
      *(half2v*)&Pb[(size_t)c * 16384] = p;
    }
  }
}

// O[b,q,d] = sum_k P[b,q,k] * VT[b,d,k], causal k range per q-tile.
// P is compact triangular f16 tiles [b][tri][128][128].
__global__ __launch_bounds__(256) void gemm_pv(const _Float16* __restrict__ Pc,
                                               const _Float16* __restrict__ VT,
                                               float* __restrict__ O) {
  __shared__ _Float16 sA[128 * 64];
  __shared__ _Float16 sB[128 * 64];
  const int tid = threadIdx.x, l = tid & 63, w = tid >> 6;
  const int dt = blockIdx.x;       // 0..7
  const int qt = 15 - blockIdx.y;  // heavy first
  const int b = blockIdx.z;
  const int wr = (w >> 1) * 64, wc = (w & 1) * 64;
  const int lr = l & 15, lk = l >> 4;
  f32x4 acc[4][4] = {};
  const _Float16* Pbase = Pc + ((size_t)b * 136 + (size_t)(qt * (qt + 1) / 2)) * 16384;
  const _Float16* Bb = VT + ((size_t)b * 1024 + dt * 128) * 2048;
  const int nk = (qt + 1) * 2;
  for (int kt = 0; kt < nk; ++kt) {
    stage_tile<1024, 256>(Pbase + (size_t)(kt >> 1) * 16384 + (kt & 1) * 64, 128, sA, tid);
    stage_tile<1024, 256>(Bb + kt * 64, 2048, sB, tid);
    __syncthreads();
#pragma unroll
    for (int kk = 0; kk < 2; ++kk) {
      half8 a[4];
#pragma unroll
      for (int i = 0; i < 4; ++i)
        a[i] = *(const half8*)&sA[(wr + i * 16 + lr) * 64 + kk * 32 + lk * 8];
#pragma unroll
      for (int j = 0; j < 4; ++j) {
        half8 bf = *(const half8*)&sB[(wc + j * 16 + lr) * 64 + kk * 32 + lk * 8];
#pragma unroll
        for (int i = 0; i < 4; ++i)
          acc[i][j] = __builtin_amdgcn_mfma_f32_16x16x32_f16(a[i], bf, acc[i][j], 0, 0, 0);
      }
    }
    __syncthreads();
  }
  const int r0 = lk * 4;
#pragma unroll
  for (int j = 0; j < 4; ++j) {
    const int cg = dt * 128 + wc + j * 16 + lr;
#pragma unroll
    for (int i = 0; i < 4; ++i) {
      const int rg = qt * 128 + wr + i * 16 + r0;
#pragma unroll
      for (int r = 0; r < 4; ++r)
        O[((size_t)b * 2048 + rg + r) * 1024 + cg] = acc[i][j][r];
    }
  }
}

extern "C" void kernel_launch(void* const* d_in, const int* in_sizes, int n_in,
                              void* d_out, int out_size, void* d_ws, size_t ws_size,
                              hipStream_t stream) {
  const float* x    = (const float*)d_in[0];
  const float* Wq_w = (const float*)d_in[1];
  const float* Wq_b = (const float*)d_in[2];
  const float* Wk_w = (const float*)d_in[3];
  const float* Wk_b = (const float*)d_in[4];
  const float* Wv_w = (const float*)d_in[5];
  const float* Wv_b = (const float*)d_in[6];
  float* out = (float*)d_out;
  char* ws = (char*)d_ws;
  // workspace layout (bytes) — total 207,618,048 B (= round-1 footprint)
  _Float16* Qh  = (_Float16*)(ws);              // 32 MiB
  _Float16* Kh  = (_Float16*)(ws + 33554432);   // 32 MiB
  _Float16* VT  = (_Float16*)(ws + 67108864);   // [8][1024][2048] f16 = 32 MiB
  _Float16* Pc  = (_Float16*)(ws + 100663296);  // compact tri P: 8*136*16384 f16 = 34 MiB
  _Float16* xh  = (_Float16*)(ws + 136314880);  // 32 MiB (dead after proj)
  _Float16* Wqh = (_Float16*)(ws + 169869312);  // 2 MiB  (dead after proj)
  _Float16* Wkh = (_Float16*)(ws + 171966464);  // 2 MiB
  _Float16* Wvh = (_Float16*)(ws + 174063616);  // 2 MiB
  float*    Sc  = (float*)(ws + 136314880);     // compact tri S f32 = 68 MiB (overlaps xh+W)

  cvt_f32_f16<<<8192, 256, 0, stream>>>(x, xh, 2097152);
  cvt_f32_f16<<<512, 256, 0, stream>>>(Wq_w, Wqh, 131072);
  cvt_f32_f16<<<512, 256, 0, stream>>>(Wk_w, Wkh, 131072);
  cvt_f32_f16<<<512, 256, 0, stream>>>(Wv_w, Wvh, 131072);
  gemm_proj<0><<<dim3(8, 128), 256, 0, stream>>>(xh, Wqh, Wq_b, Qh);
  gemm_proj<0><<<dim3(8, 128), 256, 0, stream>>>(xh, Wkh, Wk_b, Kh);
  gemm_proj<1><<<dim3(8, 128), 256, 0, stream>>>(xh, Wvh, Wv_b, VT);
  gemm_qk<<<dim3(136, 8), 256, 0, stream>>>(Qh, Kh, Sc);
  softmax_p<<<4096, 256, 0, stream>>>(Sc, Pc);
  gemm_pv<<<dim3(8, 16, 8), 256, 0, stream>>>(Pc, VT, out);
}

// Round 3
// 311.429 us; speedup vs baseline: 2.7111x; 1.2330x over previous
//
#include <hip/hip_runtime.h>

// ScaledAttention B=8,T=2048,D=1024 single-head, SCALE=1/8.
// cvt f32->f16 -> fused QKV proj (8-phase 256^2) -> causal QK^T (8-phase) ->
// row softmax -> PV (8-phase). LDS tiles as [256][32] col-half subtiles
// (64B rows -> bank-conflict-free fragment reads, clean half-tile ring).

typedef float f32x4 __attribute__((ext_vector_type(4)));
typedef _Float16 half8 __attribute__((ext_vector_type(8)));
typedef _Float16 half4 __attribute__((ext_vector_type(4)));

#define DEVINL __device__ __forceinline__
static constexpr float ATT_SCALE = 0.125f;  // 1/sqrt(1024/16)

DEVINL void gload_lds16(const _Float16* g, _Float16* l) {
  __builtin_amdgcn_global_load_lds((const __attribute__((address_space(1))) void*)g,
                                   (__attribute__((address_space(3))) void*)l, 16, 0, 0);
}

// Stage one [256][32] f16 col-half subtile (global rows stride ld) into linear LDS.
// 512 threads x 2 loads. dst = subtile base (lane offset implicit in HW).
DEVINL void stage_half(const _Float16* __restrict__ g0, int ld, _Float16* dst, int tid) {
  const int w = tid >> 6;
  const int c0 = tid, c1 = tid + 512;
  gload_lds16(g0 + (size_t)(c0 >> 2) * ld + (c0 & 3) * 8, dst + w * 512);
  gload_lds16(g0 + (size_t)(c1 >> 2) * ld + (c1 & 3) * 8, dst + 4096 + w * 512);
}

#define PH_LDA(SUB, IH) _Pragma("unroll") for (int i_ = 0; i_ < 4; ++i_) \
    a[i_] = *(const half8*)&(SUB)[aoff + (IH)*2048 + i_*512];
#define PH_LDB(SUB) _Pragma("unroll") for (int j_ = 0; j_ < 4; ++j_) \
    b[j_] = *(const half8*)&(SUB)[boff + j_*512];
#define PH_MM(IH) _Pragma("unroll") for (int i_ = 0; i_ < 4; ++i_) \
    _Pragma("unroll") for (int j_ = 0; j_ < 4; ++j_) \
      acc[(IH)*4+i_][j_] = __builtin_amdgcn_mfma_f32_16x16x32_f16(a[i_], b[j_], acc[(IH)*4+i_][j_], 0,0,0);
#define PH_MID() __builtin_amdgcn_s_barrier(); \
    asm volatile("s_waitcnt lgkmcnt(0)" ::: "memory"); \
    __builtin_amdgcn_sched_barrier(0); __builtin_amdgcn_s_setprio(1);
#define PH_END() __builtin_amdgcn_s_setprio(0); __builtin_amdgcn_s_barrier();

// 256x256 tile, BK=64, 8 waves (2M x 4N), per-wave 128x64 = acc[8][4].
// ga/gb(t,ch) -> global origin of col-half subtile ch of K-tile t. NT even, >=4.
template <class GA, class GB>
DEVINL void gemm8_core(GA ga, GB gb, int lda, int ldb, int NT,
                       _Float16* lds, int tid, f32x4 acc[8][4]) {
  const int l = tid & 63, w = tid >> 6;
  const int wm = w >> 2, wn = w & 3;
  const int lr = l & 15, lk = l >> 4;
  const int aoff = (wm * 128 + lr) * 32 + lk * 8;
  const int boff = (wn * 64 + lr) * 32 + lk * 8;
  _Float16* const A00 = lds;
  _Float16* const A01 = lds + 8192;
  _Float16* const A10 = lds + 16384;
  _Float16* const A11 = lds + 24576;
  _Float16* const B00 = lds + 32768;
  _Float16* const B01 = lds + 40960;
  _Float16* const B10 = lds + 49152;
  _Float16* const B11 = lds + 57344;
  // prologue: tile0 complete + tile1 c0
  stage_half(ga(0, 0), lda, A00, tid);
  stage_half(gb(0, 0), ldb, B00, tid);
  stage_half(ga(0, 1), lda, A01, tid);
  stage_half(gb(0, 1), ldb, B01, tid);
  stage_half(ga(1, 0), lda, A10, tid);
  stage_half(gb(1, 0), ldb, B10, tid);
  asm volatile("s_waitcnt vmcnt(4)" ::: "memory");  // tile0 (first 8 loads) landed
  __builtin_amdgcn_s_barrier();
  half8 a[4], b[4];
  const int NI = NT >> 1;
  for (int it = 0; it < NI; ++it) {
    const int T = 2 * it;
    const bool pf = (it + 1 < NI);
    // p1: tile T kk0 ih0 | stage A(T+1)c1
    PH_LDA(A00, 0); PH_LDB(B00);
    stage_half(ga(T + 1, 1), lda, A11, tid);
    PH_MID(); PH_MM(0); PH_END();
    // p2: tile T kk0 ih1 | stage B(T+1)c1
    PH_LDA(A00, 1);
    stage_half(gb(T + 1, 1), ldb, B11, tid);
    PH_MID(); PH_MM(1); PH_END();
    // p3: tile T kk1 ih0 | stage A(T+2)c0
    PH_LDA(A01, 0); PH_LDB(B01);
    if (pf) stage_half(ga(T + 2, 0), lda, A00, tid);
    PH_MID(); PH_MM(0); PH_END();
    // p4: tile T kk1 ih1 | stage B(T+2)c0 | counted wait
    PH_LDA(A01, 1);
    if (pf) stage_half(gb(T + 2, 0), ldb, B00, tid);
    PH_MID(); PH_MM(1);
    __builtin_amdgcn_s_setprio(0);
    if (it == NI - 1) { asm volatile("s_waitcnt vmcnt(0)" ::: "memory"); }
    else              { asm volatile("s_waitcnt vmcnt(2)" ::: "memory"); }
    __builtin_amdgcn_s_barrier();
    // p5: tile T+1 kk0 ih0 | stage A(T+2)c1
    PH_LDA(A10, 0); PH_LDB(B10);
    if (pf) stage_half(ga(T + 2, 1), lda, A01, tid);
    PH_MID(); PH_MM(0); PH_END();
    // p6: tile T+1 kk0 ih1 | stage B(T+2)c1
    PH_LDA(A10, 1);
    if (pf) stage_half(gb(T + 2, 1), ldb, B01, tid);
    PH_MID(); PH_MM(1); PH_END();
    // p7: tile T+1 kk1 ih0 | stage A(T+3)c0
    PH_LDA(A11, 0); PH_LDB(B11);
    if (pf) stage_half(ga(T + 3, 0), lda, A10, tid);
    PH_MID(); PH_MM(0); PH_END();
    // p8: tile T+1 kk1 ih1 | stage B(T+3)c0 | counted wait
    PH_LDA(A11, 1);
    if (pf) stage_half(gb(T + 3, 0), ldb, B10, tid);
    PH_MID(); PH_MM(1);
    __builtin_amdgcn_s_setprio(0);
    asm volatile("s_waitcnt vmcnt(2)" ::: "memory");
    __builtin_amdgcn_s_barrier();
  }
}

__global__ __launch_bounds__(256) void cvt_f32_f16(const float* __restrict__ in,
                                                   _Float16* __restrict__ out, int n8) {
  int i = blockIdx.x * 256 + threadIdx.x;
  if (i >= n8) return;
  const float4* p = (const float4*)in + (size_t)i * 2;
  float4 v0 = p[0], v1 = p[1];
  half8 h;
  h[0] = (_Float16)v0.x; h[1] = (_Float16)v0.y; h[2] = (_Float16)v0.z; h[3] = (_Float16)v0.w;
  h[4] = (_Float16)v1.x; h[5] = (_Float16)v1.y; h[6] = (_Float16)v1.z; h[7] = (_Float16)v1.w;
  *((half8*)out + i) = h;
}

// Fused QKV projection: C[m,n]=sum_k x[m,k]*W[n,k]+b[n], M=16384, N=3072(Q|K|V), K=1024.
__global__ __launch_bounds__(512) void gemm_qkv(
    const _Float16* __restrict__ xh, const _Float16* __restrict__ Wqh,
    const _Float16* __restrict__ Wkh, const _Float16* __restrict__ Wvh,
    const float* __restrict__ bq, const float* __restrict__ bk,
    const float* __restrict__ bv, _Float16* __restrict__ Qh,
    _Float16* __restrict__ Kh, _Float16* __restrict__ VT) {
  __shared__ _Float16 lds[65536];
  const int tid = threadIdx.x;
  const int bid = blockIdx.x;
  const int swz = (bid & 7) * 96 + (bid >> 3);  // XCD swizzle, 768%8==0
  const int mt = swz / 12, nt = swz % 12;
  const int sel = nt >> 2;
  const _Float16* Wsel = sel == 0 ? Wqh : (sel == 1 ? Wkh : Wvh);
  const float* bsel = sel == 0 ? bq : (sel == 1 ? bk : bv);
  const _Float16* Ab = xh + (size_t)mt * 256 * 1024;
  const _Float16* Bb = Wsel + (size_t)(nt & 3) * 256 * 1024;
  f32x4 acc[8][4] = {};
  auto ga = [&](int t, int ch) { return Ab + t * 64 + ch * 32; };
  auto gb = [&](int t, int ch) { return Bb + t * 64 + ch * 32; };
  gemm8_core(ga, gb, 1024, 1024, 16, lds, tid, acc);
  const int l = tid & 63, w = tid >> 6;
  const int wm = w >> 2, wn = w & 3;
  const int lr = l & 15, lk = l >> 4;
#pragma unroll
  for (int j = 0; j < 4; ++j) {
    const int cm = (nt & 3) * 256 + wn * 64 + j * 16 + lr;
    const float bvv = bsel[cm];
#pragma unroll
    for (int ii = 0; ii < 8; ++ii) {
      const int rg = mt * 256 + wm * 128 + ii * 16 + lk * 4;
      if (sel < 2) {
        _Float16* Out = sel == 0 ? Qh : Kh;
#pragma unroll
        for (int r = 0; r < 4; ++r)
          Out[(size_t)(rg + r) * 1024 + cm] = (_Float16)(acc[ii][j][r] + bvv);
      } else {
        const int bb = rg >> 11, t0 = rg & 2047;
        half4 v;
#pragma unroll
        for (int r = 0; r < 4; ++r) v[r] = (_Float16)(acc[ii][j][r] + bvv);
        *(half4*)&VT[((size_t)bb * 1024 + cm) * 2048 + t0] = v;
      }
    }
  }
}

// Causal QK^T: blockIdx.x = tri tile (qt,jt<=qt) of 256^2, writes compact f32 S
// [b][tri36][256][256], scaled, -inf above diagonal.
__global__ __launch_bounds__(512) void gemm_qk(const _Float16* __restrict__ Qh,
                                               const _Float16* __restrict__ Kh,
                                               float* __restrict__ Sc) {
  __shared__ _Float16 lds[65536];
  const int tid = threadIdx.x;
  const int idx = blockIdx.x, bb = blockIdx.y;
  int qt = 0;
  while ((qt + 1) * (qt + 2) / 2 <= idx) ++qt;
  const int jt = idx - qt * (qt + 1) / 2;
  const _Float16* Ab = Qh + ((size_t)bb * 2048 + qt * 256) * 1024;
  const _Float16* Bb = Kh + ((size_t)bb * 2048 + jt * 256) * 1024;
  f32x4 acc[8][4] = {};
  auto ga = [&](int t, int ch) { return Ab + t * 64 + ch * 32; };
  auto gb = [&](int t, int ch) { return Bb + t * 64 + ch * 32; };
  gemm8_core(ga, gb, 1024, 1024, 16, lds, tid, acc);
  const int l = tid & 63, w = tid >> 6;
  const int wm = w >> 2, wn = w & 3;
  const int lr = l & 15, lk = l >> 4;
  float* St = Sc + ((size_t)bb * 36 + idx) * 65536;
  const float NINF = -__builtin_inff();
#pragma unroll
  for (int j = 0; j < 4; ++j) {
    const int ck = wn * 64 + j * 16 + lr;
    const int kg = jt * 256 + ck;
#pragma unroll
    for (int ii = 0; ii < 8; ++ii) {
#pragma unroll
      for (int r = 0; r < 4; ++r) {
        const int rq = wm * 128 + ii * 16 + lk * 4 + r;
        const int qg = qt * 256 + rq;
        St[(size_t)rq * 256 + ck] = (kg <= qg) ? acc[ii][j][r] * ATT_SCALE : NINF;
      }
    }
  }
}

// One wave per row: in-register softmax over compact S row, writes f16 P.
__global__ __launch_bounds__(256) void softmax_p(const float* __restrict__ Sc,
                                                 _Float16* __restrict__ Pc) {
  const int l = threadIdx.x & 63;
  const int gid = blockIdx.x * 4 + (threadIdx.x >> 6);
  const int b = gid >> 11, q = gid & 2047;
  const int qt = q >> 8, rq = q & 255;
  const int ntile = qt + 1;
  const size_t base = ((size_t)b * 36 + (size_t)(qt * (qt + 1) / 2)) * 65536 +
                      (size_t)rq * 256 + l * 4;
  float vx[32];
  float m = -__builtin_inff();
#pragma unroll
  for (int c = 0; c < 8; ++c) {
    float4 t = {-__builtin_inff(), -__builtin_inff(), -__builtin_inff(), -__builtin_inff()};
    if (c < ntile) t = *(const float4*)&Sc[base + (size_t)c * 65536];
    vx[4 * c] = t.x; vx[4 * c + 1] = t.y; vx[4 * c + 2] = t.z; vx[4 * c + 3] = t.w;
    m = fmaxf(m, fmaxf(fmaxf(t.x, t.y), fmaxf(t.z, t.w)));
  }
#pragma unroll
  for (int s = 1; s < 64; s <<= 1) m = fmaxf(m, __shfl_xor(m, s, 64));
  float sum = 0.f;
#pragma unroll
  for (int i = 0; i < 32; ++i) { vx[i] = __expf(vx[i] - m); sum += vx[i]; }
#pragma unroll
  for (int s = 1; s < 64; s <<= 1) sum += __shfl_xor(sum, s, 64);
  const float inv = 1.f / sum;
  _Float16* Pb = Pc + base;
#pragma unroll
  for (int c = 0; c < 8; ++c) {
    if (c < ntile) {
      half4 p;
      p[0] = (_Float16)(vx[4 * c] * inv);
      p[1] = (_Float16)(vx[4 * c + 1] * inv);
      p[2] = (_Float16)(vx[4 * c + 2] * inv);
      p[3] = (_Float16)(vx[4 * c + 3] * inv);
      *(half4*)&Pb[(size_t)c * 65536] = p;
    }
  }
}

// O[b,q,d] = sum_k P[b,q,k]*VT[b,d,k] over causal k range. P compact tri f16.
__global__ __launch_bounds__(512) void gemm_pv(const _Float16* __restrict__ Pc,
                                               const _Float16* __restrict__ VT,
                                               float* __restrict__ O) {
  __shared__ _Float16 lds[65536];
  const int tid = threadIdx.x;
  const int dt = blockIdx.x, qt = 7 - blockIdx.y, b = blockIdx.z;
  const _Float16* Pb = Pc + ((size_t)b * 36 + (size_t)(qt * (qt + 1) / 2)) * 65536;
  const _Float16* Vb = VT + ((size_t)b * 1024 + dt * 256) * 2048;
  f32x4 acc[8][4] = {};
  auto ga = [&](int t, int ch) {
    return Pb + (size_t)(t >> 2) * 65536 + (t & 3) * 64 + ch * 32;
  };
  auto gb = [&](int t, int ch) { return Vb + t * 64 + ch * 32; };
  gemm8_core(ga, gb, 256, 2048, (qt + 1) * 4, lds, tid, acc);
  const int l = tid & 63, w = tid >> 6;
  const int wm = w >> 2, wn = w & 3;
  const int lr = l & 15, lk = l >> 4;
#pragma unroll
  for (int j = 0; j < 4; ++j) {
    const int cg = dt * 256 + wn * 64 + j * 16 + lr;
#pragma unroll
    for (int ii = 0; ii < 8; ++ii) {
      const int rg = qt * 256 + wm * 128 + ii * 16 + lk * 4;
#pragma unroll
      for (int r = 0; r < 4; ++r)
        O[((size_t)b * 2048 + rg + r) * 1024 + cg] = acc[ii][j][r];
    }
  }
}

extern "C" void kernel_launch(void* const* d_in, const int* in_sizes, int n_in,
                              void* d_out, int out_size, void* d_ws, size_t ws_size,
                              hipStream_t stream) {
  const float* x    = (const float*)d_in[0];
  const float* Wq_w = (const float*)d_in[1];
  const float* Wq_b = (const float*)d_in[2];
  const float* Wk_w = (const float*)d_in[3];
  const float* Wk_b = (const float*)d_in[4];
  const float* Wv_w = (const float*)d_in[5];
  const float* Wv_b = (const float*)d_in[6];
  float* out = (float*)d_out;
  char* ws = (char*)d_ws;
  // Workspace (peak 176,160,768 B):
  // [0, 75.5MB): Sc (f32 compact tri S) -- aliases xh + weights (dead after proj)
  _Float16* xh  = (_Float16*)(ws);
  _Float16* Wqh = (_Float16*)(ws + 33554432);
  _Float16* Wkh = (_Float16*)(ws + 35651584);
  _Float16* Wvh = (_Float16*)(ws + 37748736);
  float*    Sc  = (float*)(ws);
  // [75.5MB, 142.6MB): Qh, Kh -- aliased later by Pc (dead after QK^T)
  _Float16* Qh  = (_Float16*)(ws + 75497472);
  _Float16* Kh  = (_Float16*)(ws + 109051904);
  _Float16* Pc  = (_Float16*)(ws + 75497472);
  // [142.6MB, 176.2MB): VT
  _Float16* VT  = (_Float16*)(ws + 142606336);

  cvt_f32_f16<<<8192, 256, 0, stream>>>(x, xh, 2097152);
  cvt_f32_f16<<<512, 256, 0, stream>>>(Wq_w, Wqh, 131072);
  cvt_f32_f16<<<512, 256, 0, stream>>>(Wk_w, Wkh, 131072);
  cvt_f32_f16<<<512, 256, 0, stream>>>(Wv_w, Wvh, 131072);
  gemm_qkv<<<768, 512, 0, stream>>>(xh, Wqh, Wkh, Wvh, Wq_b, Wk_b, Wv_b, Qh, Kh, VT);
  gemm_qk<<<dim3(36, 8), 512, 0, stream>>>(Qh, Kh, Sc);
  softmax_p<<<4096, 256, 0, stream>>>(Sc, Pc);
  gemm_pv<<<dim3(4, 8, 8), 512, 0, stream>>>(Pc, VT, out);
}